// Round 8
// baseline (274.439 us; speedup 1.0000x reference)
//
#include <hip/hip_runtime.h>

#define B_SZ 256
#define S_LEN 512
#define NT 128
#define PAD 127
#define LN2F 0.69314718055994530942f
#define RENORM 0x1p-62f

typedef float v2f __attribute__((ext_vector_type(2)));

__device__ __forceinline__ float bcastf(float v, int k) {
    return __uint_as_float((unsigned)__builtin_amdgcn_readlane((int)__float_as_uint(v), k));
}

// Barrier draining only LDS (lgkmcnt), NOT vmcnt — emission prefetch loads
// stay in flight across steps.
__device__ __forceinline__ void lds_barrier() {
    asm volatile("s_waitcnt lgkmcnt(0)\n\ts_barrier" ::: "memory");
}

// r7 skeleton (2 waves, k-split 64, 1-float exchange) with the broadcast
// engine re-packed over K-PAIRS: colX[p]={expT[2p][l],expT[2p+1][l]},
// colY[p]={expT[2p][64+l],expT[2p+1][64+l]}; multiplier {a[2p],a[2p+1]} is
// a natural pair from TWO readlanes — no splat v_movs. Cost: 2 readlane +
// 2 pkfma per 2k covering both j-halves = 2 instr/k (r7 measured 4.4/k).
// Horizontal .x+.y fold once per step recovers the k-sum.
__global__ __launch_bounds__(128, 1) void crf_fused(
    const float* __restrict__ em,      // (B,S,T)
    const int*   __restrict__ tags,    // (B,S)
    const float* __restrict__ startT,  // (T)
    const float* __restrict__ endT,    // (T)
    const float* __restrict__ trans,   // (T,T)
    float* __restrict__ out)
{
    const int b   = blockIdx.x;
    const int tid = threadIdx.x;
    const int w   = tid >> 6;          // wave 0..1
    const int l   = tid & 63;          // lane
    const int hw  = 64 * w;            // this wave's half/k-slice base

    __shared__ float xchg[2][2][64];   // [parity][dst wave][lane]
    __shared__ float maskv[S_LEN];     // per-step mask as float
    __shared__ float aF[NT];           // final alpha gather
    __shared__ float nred[2];
    __shared__ int   cred[2];

    const float* em_b = em + (size_t)b * S_LEN * NT;
    const int*   tg_b = tags + (size_t)b * S_LEN;

    // ---- stage per-step masks ----
    for (int q = tid; q < S_LEN; q += 128)
        maskv[q] = (tg_b[q] != PAD) ? 1.0f : 0.0f;

    // ---- numerator partial + valid count (wave w covers chunks 4w..4w+3) ----
    float numSum = 0.f;
    int   cnt    = 0;
    #pragma unroll
    for (int q = 0; q < 4; ++q) {
        int t  = 64 * (4 * w + q) + l;
        int tv = tg_b[t];
        cnt += (tv != PAD) ? 1 : 0;
        float emg = em_b[(size_t)t * NT + tv];
        if (t == 0) {
            numSum += startT[tv] + emg;
        } else {
            int tp = tg_b[t - 1];
            float v = trans[tp * NT + tv] + emg;
            numSum += (tv != PAD) ? v : 0.f;
        }
    }
    #pragma unroll
    for (int off = 32; off > 0; off >>= 1) {
        numSum += __shfl_down(numSum, off, 64);
        cnt    += __shfl_down(cnt, off, 64);
    }
    if (l == 0) { nred[w] = numSum; cred[w] = cnt; }

    // ---- k-pair column registers for this wave's slice ----
    // colX[p] = {expT[hw+2p][l],    expT[hw+2p+1][l]}      (j = l)
    // colY[p] = {expT[hw+2p][64+l], expT[hw+2p+1][64+l]}   (j = 64+l)
    v2f colX[32], colY[32];
    #pragma unroll
    for (int p = 0; p < 32; ++p) {
        colX[p].x = __expf(trans[(hw + 2 * p)     * NT + l]);
        colX[p].y = __expf(trans[(hw + 2 * p + 1) * NT + l]);
        colY[p].x = __expf(trans[(hw + 2 * p)     * NT + 64 + l]);
        colY[p].y = __expf(trans[(hw + 2 * p + 1) * NT + 64 + l]);
    }

    // ---- alpha_0: lane i of wave w holds alpha[hw+i] ----
    float aO = __expf(startT[hw + l] + em_b[hw + l]);

    // ---- em pipeline (own half only): slot s holds em[t=s+1 (mod 8)][hw+l] ----
    const float* emj = em_b + hw + l;
    float rE0 = emj[1 * NT], rE1 = emj[2 * NT], rE2 = emj[3 * NT], rE3 = emj[4 * NT];
    float rE4 = emj[5 * NT], rE5 = emj[6 * NT], rE6 = emj[7 * NT], rE7 = emj[8 * NT];

    __syncthreads();   // maskv + nred visible; one-time full barrier

#define STEP(SL, T, RN)                                                      \
  {                                                                          \
    const int t_   = (T);                                                    \
    const int par_ = t_ & 1;                                                 \
    int   tn_ = (t_ + 8 < S_LEN) ? t_ + 8 : S_LEN - 1;                       \
    float nE_ = emj[(size_t)tn_ * NT];                                       \
    float mv_ = maskv[t_];                                                   \
    float e_  = __expf(rE##SL);                                              \
    rE##SL = nE_;                                                            \
    v2f x0_ = {0.f,0.f}, x1_ = {0.f,0.f};                                    \
    v2f y0_ = {0.f,0.f}, y1_ = {0.f,0.f};                                    \
    _Pragma("unroll")                                                        \
    for (int p_ = 0; p_ < 32; p_ += 2) {                                     \
      v2f apA_ = {bcastf(aO, 2 * p_),     bcastf(aO, 2 * p_ + 1)};           \
      v2f apB_ = {bcastf(aO, 2 * p_ + 2), bcastf(aO, 2 * p_ + 3)};           \
      x0_ += apA_ * colX[p_];     y0_ += apA_ * colY[p_];                    \
      x1_ += apB_ * colX[p_ + 1]; y1_ += apB_ * colY[p_ + 1];                \
    }                                                                        \
    v2f px_ = x0_ + x1_;                                                     \
    v2f py_ = y0_ + y1_;                                                     \
    float pX_ = px_.x + px_.y;          /* partial for j = l      */         \
    float pY_ = py_.x + py_.y;          /* partial for j = 64 + l */         \
    float keep_ = (w == 0) ? pX_ : pY_;                                      \
    float ship_ = (w == 0) ? pY_ : pX_;                                      \
    xchg[par_][1 ^ w][l] = ship_;       /* one ds_write_b32 */               \
    lds_barrier();                                                           \
    float oth_  = xchg[par_][w][l];     /* one ds_read_b32 */                \
    float comb_ = (keep_ + oth_) * e_;  /* fold exp(em[own half]) */         \
    aO = (mv_ != 0.0f) ? comb_ : aO;                                         \
    if (RN) aO *= RENORM;                                                    \
  }

    // chunk 0: t = 1..7  (slot = (t-1)&7)
    STEP(0, 1, false) STEP(1, 2, false) STEP(2, 3, false) STEP(3, 4, false)
    STEP(4, 5, false) STEP(5, 6, false) STEP(6, 7, false)

    // chunks 1..63: t = 8c .. 8c+7 ; renorm at t = 8c (63 renorms total)
    for (int c = 1; c < 64; ++c) {
        const int t0 = c * 8;
        STEP(7, t0,     true)
        STEP(0, t0 + 1, false) STEP(1, t0 + 2, false) STEP(2, t0 + 3, false)
        STEP(3, t0 + 4, false) STEP(4, t0 + 5, false) STEP(5, t0 + 6, false)
        STEP(6, t0 + 7, false)
    }
#undef STEP

    // ---- finalize: gather halves, wave 0 computes denominator ----
    aF[hw + l] = aO;
    __syncthreads();

    if (w == 0) {
        float ax = aF[l];
        float ay = aF[64 + l];
        float pe = ax * __expf(endT[l]) + ay * __expf(endT[64 + l]);
        #pragma unroll
        for (int off = 32; off > 0; off >>= 1)
            pe += __shfl_down(pe, off, 64);
        if (l == 0) {
            int   cT   = cred[0] + cred[1];
            int   last = tg_b[cT - 1];
            float num  = nred[0] + nred[1] + endT[last];
            float den  = 63.0f * 62.0f * LN2F + logf(pe);
            atomicAdd(out, (num - den) * (1.0f / (float)B_SZ));
        }
    }
}

extern "C" void kernel_launch(void* const* d_in, const int* in_sizes, int n_in,
                              void* d_out, int out_size, void* d_ws, size_t ws_size,
                              hipStream_t stream) {
    const float* em     = (const float*)d_in[0];
    const int*   tags   = (const int*)d_in[1];
    const float* startT = (const float*)d_in[2];
    const float* endT   = (const float*)d_in[3];
    const float* trans  = (const float*)d_in[4];
    float* out = (float*)d_out;

    hipMemsetAsync(out, 0, sizeof(float), stream);
    crf_fused<<<B_SZ, 128, 0, stream>>>(em, tags, startT, endT, trans, out);
}

// Round 9
// 248.892 us; speedup vs baseline: 1.1026x; 1.1026x over previous
//
#include <hip/hip_runtime.h>

#define B_SZ 256
#define S_LEN 512
#define NT 128
#define PAD 127
#define LN2F 0.69314718055994530942f
#define RENORM 0x1p-62f

typedef float v2f __attribute__((ext_vector_type(2)));

__device__ __forceinline__ float bcastf(float v, int k) {
    return __uint_as_float((unsigned)__builtin_amdgcn_readlane((int)__float_as_uint(v), k));
}

// Barrier draining only LDS (lgkmcnt), NOT vmcnt — emission prefetch loads
// stay in flight across steps.
__device__ __forceinline__ void lds_barrier() {
    asm volatile("s_waitcnt lgkmcnt(0)\n\ts_barrier" ::: "memory");
}

// Bidirectional split: block 2b = FORWARD chain of batch b (steps 1..255 ->
// alpha_255), block 2b+1 = BACKWARD chain (steps 511..256 -> beta_255 with
// beta_511 = exp(endT)). den = log(dot(alpha_255, beta_255)) + 62*62*ln2
// (31 renorms each side). Masked step = identity on both sides. Each chain
// uses the r7 engine: 2 waves, k-split 64, readlane broadcast, v_pk_fma,
// 1-float/lane LDS exchange, one 2-wave barrier/step. Backward differs only
// in col regs (transposed rows of exp(trans)) and em folded BEFORE the
// matvec. Chains live in separate blocks -> independent barriers (no
// lockstep coupling, r5 lesson); 512 blocks = 2 blocks/CU co-resident.
__global__ __launch_bounds__(128, 1) void crf_fb(
    const float* __restrict__ em,      // (B,S,T)
    const int*   __restrict__ tags,    // (B,S)
    const float* __restrict__ startT,  // (T)
    const float* __restrict__ endT,    // (T)
    const float* __restrict__ trans,   // (T,T)
    float* __restrict__ out,
    float* __restrict__ wsA,           // (B,NT) alpha_255
    float* __restrict__ wsB)           // (B,NT) beta_255
{
    const int bid = blockIdx.x;
    const int b   = bid >> 1;
    const int dir = bid & 1;           // 0 = forward, 1 = backward
    const int tid = threadIdx.x;
    const int w   = tid >> 6;          // wave 0..1
    const int l   = tid & 63;          // lane
    const int hw  = 64 * w;            // this wave's half/k-slice base

    __shared__ float xchg[2][2][64];   // [parity][dst wave][lane]
    __shared__ float maskv[S_LEN];     // per-step mask as float
    __shared__ float nred[2];
    __shared__ int   cred[2];

    const float* em_b = em + (size_t)b * S_LEN * NT;
    const int*   tg_b = tags + (size_t)b * S_LEN;
    const float* emj  = em_b + hw + l;

    // ---- column registers (direction-dependent orientation) ----
    v2f col[64];
    if (dir == 0) {
        #pragma unroll
        for (int i = 0; i < 64; ++i) {
            col[i].x = __expf(trans[(hw + i) * NT + l]);
            col[i].y = __expf(trans[(hw + i) * NT + 64 + l]);
        }
    } else {
        #pragma unroll
        for (int i = 0; i < 64; ++i) {
            col[i].x = __expf(trans[l * NT + hw + i]);
            col[i].y = __expf(trans[(64 + l) * NT + hw + i]);
        }
    }

    float aO;      // fwd: alpha[hw+l]; bwd: beta[hw+l]
    float rE0, rE1, rE2, rE3, rE4, rE5, rE6, rE7;

    if (dir == 0) {
        // ---- masks for t in [1,256) ----
        for (int q = tid; q < 256; q += 128)
            maskv[q] = (tg_b[q] != PAD) ? 1.0f : 0.0f;

        // ---- numerator partial + valid count ----
        float numSum = 0.f;
        int   cnt    = 0;
        #pragma unroll
        for (int q = 0; q < 4; ++q) {
            int t  = 64 * (4 * w + q) + l;
            int tv = tg_b[t];
            cnt += (tv != PAD) ? 1 : 0;
            float emg = em_b[(size_t)t * NT + tv];
            if (t == 0) {
                numSum += startT[tv] + emg;
            } else {
                int tp = tg_b[t - 1];
                float v = trans[tp * NT + tv] + emg;
                numSum += (tv != PAD) ? v : 0.f;
            }
        }
        #pragma unroll
        for (int off = 32; off > 0; off >>= 1) {
            numSum += __shfl_down(numSum, off, 64);
            cnt    += __shfl_down(cnt, off, 64);
        }
        if (l == 0) { nred[w] = numSum; cred[w] = cnt; }

        aO = __expf(startT[hw + l] + em_b[hw + l]);
        rE0 = emj[1 * NT]; rE1 = emj[2 * NT]; rE2 = emj[3 * NT]; rE3 = emj[4 * NT];
        rE4 = emj[5 * NT]; rE5 = emj[6 * NT]; rE6 = emj[7 * NT]; rE7 = emj[8 * NT];
    } else {
        // ---- masks for t in [256,512) ----
        for (int q = 256 + tid; q < 512; q += 128)
            maskv[q] = (tg_b[q] != PAD) ? 1.0f : 0.0f;

        aO = __expf(endT[hw + l]);     // beta_511
        rE0 = emj[511 * NT]; rE1 = emj[510 * NT]; rE2 = emj[509 * NT]; rE3 = emj[508 * NT];
        rE4 = emj[507 * NT]; rE5 = emj[506 * NT]; rE6 = emj[505 * NT]; rE7 = emj[504 * NT];
    }

    __syncthreads();   // maskv (+ nred) visible; one-time full barrier

    if (dir == 0) {
        // emit numerator early (off the chain's critical path)
        if (w == 0 && l == 0) {
            int   cT   = cred[0] + cred[1];
            int   last = tg_b[cT - 1];
            float num  = nred[0] + nred[1] + endT[last];
            atomicAdd(out, num * (1.0f / (float)B_SZ));
        }

#define STEP(SL, T, RN)                                                      \
  {                                                                          \
    const int t_   = (T);                                                    \
    const int par_ = t_ & 1;                                                 \
    int   tn_ = (t_ + 8 < S_LEN) ? t_ + 8 : S_LEN - 1;                       \
    float nE_ = emj[(size_t)tn_ * NT];                                       \
    float mv_ = maskv[t_];                                                   \
    float e_  = __expf(rE##SL);                                              \
    rE##SL = nE_;                                                            \
    v2f a0_ = {0.f,0.f}, a1_ = {0.f,0.f}, a2_ = {0.f,0.f}, a3_ = {0.f,0.f};  \
    _Pragma("unroll")                                                        \
    for (int i_ = 0; i_ < 64; i_ += 4) {                                     \
      float s0_ = bcastf(aO, i_);                                            \
      float s1_ = bcastf(aO, i_ + 1);                                        \
      float s2_ = bcastf(aO, i_ + 2);                                        \
      float s3_ = bcastf(aO, i_ + 3);                                        \
      a0_ += (v2f){s0_, s0_} * col[i_];                                      \
      a1_ += (v2f){s1_, s1_} * col[i_ + 1];                                  \
      a2_ += (v2f){s2_, s2_} * col[i_ + 2];                                  \
      a3_ += (v2f){s3_, s3_} * col[i_ + 3];                                  \
    }                                                                        \
    v2f p_ = (a0_ + a1_) + (a2_ + a3_);                                      \
    float keep_ = (w == 0) ? p_.x : p_.y;                                    \
    float ship_ = (w == 0) ? p_.y : p_.x;                                    \
    xchg[par_][1 ^ w][l] = ship_;                                            \
    lds_barrier();                                                           \
    float oth_  = xchg[par_][w][l];                                          \
    float comb_ = (keep_ + oth_) * e_;   /* fold exp(em_t[own]) AFTER */     \
    aO = (mv_ != 0.0f) ? comb_ : aO;                                         \
    if (RN) aO *= RENORM;                                                    \
  }

        // chunk 0: t = 1..7
        STEP(0, 1, false) STEP(1, 2, false) STEP(2, 3, false) STEP(3, 4, false)
        STEP(4, 5, false) STEP(5, 6, false) STEP(6, 7, false)
        // chunks 1..31: t = 8c..8c+7, renorm at t = 8c  (31 renorms)
        for (int c = 1; c < 32; ++c) {
            const int t0 = c * 8;
            STEP(7, t0,     true)
            STEP(0, t0 + 1, false) STEP(1, t0 + 2, false) STEP(2, t0 + 3, false)
            STEP(3, t0 + 4, false) STEP(4, t0 + 5, false) STEP(5, t0 + 6, false)
            STEP(6, t0 + 7, false)
        }
#undef STEP
        wsA[(size_t)b * NT + hw + l] = aO;   // alpha_255 (scaled 2^(-62*31))
    } else {

#define STEPB(SL, T, RN)                                                     \
  {                                                                          \
    const int t_   = (T);                                                    \
    const int par_ = t_ & 1;                                                 \
    int   tn_ = (t_ - 8 >= 256) ? t_ - 8 : 256;                              \
    float nE_ = emj[(size_t)tn_ * NT];                                       \
    float mv_ = maskv[t_];                                                   \
    float e_  = __expf(rE##SL);                                              \
    rE##SL = nE_;                                                            \
    float v_ = aO * e_;                  /* fold exp(em_t[own]) BEFORE */    \
    v2f a0_ = {0.f,0.f}, a1_ = {0.f,0.f}, a2_ = {0.f,0.f}, a3_ = {0.f,0.f};  \
    _Pragma("unroll")                                                        \
    for (int i_ = 0; i_ < 64; i_ += 4) {                                     \
      float s0_ = bcastf(v_, i_);                                            \
      float s1_ = bcastf(v_, i_ + 1);                                        \
      float s2_ = bcastf(v_, i_ + 2);                                        \
      float s3_ = bcastf(v_, i_ + 3);                                        \
      a0_ += (v2f){s0_, s0_} * col[i_];                                      \
      a1_ += (v2f){s1_, s1_} * col[i_ + 1];                                  \
      a2_ += (v2f){s2_, s2_} * col[i_ + 2];                                  \
      a3_ += (v2f){s3_, s3_} * col[i_ + 3];                                  \
    }                                                                        \
    v2f p_ = (a0_ + a1_) + (a2_ + a3_);                                      \
    float keep_ = (w == 0) ? p_.x : p_.y;                                    \
    float ship_ = (w == 0) ? p_.y : p_.x;                                    \
    xchg[par_][1 ^ w][l] = ship_;                                            \
    lds_barrier();                                                           \
    float oth_  = xchg[par_][w][l];                                          \
    float comb_ = keep_ + oth_;                                              \
    aO = (mv_ != 0.0f) ? comb_ : aO;                                         \
    if (RN) aO *= RENORM;                                                    \
  }

        // chunk 0: t = 511..504 (8 steps, no renorm)
        STEPB(0, 511, false) STEPB(1, 510, false) STEPB(2, 509, false)
        STEPB(3, 508, false) STEPB(4, 507, false) STEPB(5, 506, false)
        STEPB(6, 505, false) STEPB(7, 504, false)
        // chunks 1..31: t = 511-8c .. 504-8c, renorm at first (31 renorms)
        for (int c = 1; c < 32; ++c) {
            const int t0 = 511 - 8 * c;
            STEPB(0, t0,     true)
            STEPB(1, t0 - 1, false) STEPB(2, t0 - 2, false) STEPB(3, t0 - 3, false)
            STEPB(4, t0 - 4, false) STEPB(5, t0 - 5, false) STEPB(6, t0 - 6, false)
            STEPB(7, t0 - 7, false)
        }
#undef STEPB
        wsB[(size_t)b * NT + hw + l] = aO;   // beta_255 (scaled 2^(-62*31))
    }
}

// Join: den_b = log(dot(alpha_255, beta_255)) + 62*62*ln2; out -= den_b / B.
__global__ __launch_bounds__(64, 1) void crf_combine(
    const float* __restrict__ wsA,
    const float* __restrict__ wsB,
    float* __restrict__ out)
{
    const int b = blockIdx.x;
    const int l = threadIdx.x;
    const float* A  = wsA + (size_t)b * NT;
    const float* Bv = wsB + (size_t)b * NT;
    float pe = A[l] * Bv[l] + A[64 + l] * Bv[64 + l];
    #pragma unroll
    for (int off = 32; off > 0; off >>= 1)
        pe += __shfl_down(pe, off, 64);
    if (l == 0) {
        float den = 62.0f * 62.0f * LN2F + logf(pe);
        atomicAdd(out, den * (-1.0f / (float)B_SZ));
    }
}

extern "C" void kernel_launch(void* const* d_in, const int* in_sizes, int n_in,
                              void* d_out, int out_size, void* d_ws, size_t ws_size,
                              hipStream_t stream) {
    const float* em     = (const float*)d_in[0];
    const int*   tags   = (const int*)d_in[1];
    const float* startT = (const float*)d_in[2];
    const float* endT   = (const float*)d_in[3];
    const float* trans  = (const float*)d_in[4];
    float* out = (float*)d_out;
    float* wsA = (float*)d_ws;
    float* wsB = wsA + (size_t)B_SZ * NT;

    hipMemsetAsync(out, 0, sizeof(float), stream);
    crf_fb<<<B_SZ * 2, 128, 0, stream>>>(em, tags, startT, endT, trans, out, wsA, wsB);
    crf_combine<<<B_SZ, 64, 0, stream>>>(wsA, wsB, out);
}

// Round 10
// 204.671 us; speedup vs baseline: 1.3409x; 1.2161x over previous
//
#include <hip/hip_runtime.h>

#define B_SZ 256
#define S_LEN 512
#define NT 128
#define PAD 127
#define LN2F 0.69314718055994530942f
#define RENORM 0x1p-62f

__device__ __forceinline__ float bcastf(float v, int k) {
    return __uint_as_float((unsigned)__builtin_amdgcn_readlane((int)__float_as_uint(v), k));
}

// Barrier draining only LDS (lgkmcnt), NOT vmcnt — emission prefetch loads
// stay in flight across steps.
__device__ __forceinline__ void lds_barrier() {
    asm volatile("s_waitcnt lgkmcnt(0)\n\ts_barrier" ::: "memory");
}

// One block per batch, FOUR waves on four SIMDs: waves 0-1 = FORWARD team
// (alpha, steps t=1..255 + 1 dummy), waves 2-3 = BACKWARD team (beta, steps
// t=511..256). Teams share the per-step s_barrier (identical work per step,
// parallel issue on distinct SIMDs — unlike r9's 2-blocks/CU which packed
// both chains onto the same SIMD pair and serialized issue, 1584 cyc/step).
// Within a team: r7 engine (k-split 64/wave, 1-float/lane LDS exchange) with
// a 3-instr/k inner loop: readlane (SGPR) feeds v_fmac src0 directly; col
// arrays may stay AGPR-homed (VALU reads AGPRs natively on gfx950).
// den = log(dot(alpha_255, beta_255)) + 62*62*ln2 (31 renorms per team).
// Combine happens in-block: no second kernel, no workspace.
__global__ __launch_bounds__(256, 1) void crf_fb(
    const float* __restrict__ em,      // (B,S,T)
    const int*   __restrict__ tags,    // (B,S)
    const float* __restrict__ startT,  // (T)
    const float* __restrict__ endT,    // (T)
    const float* __restrict__ trans,   // (T,T)
    float* __restrict__ out)
{
    const int b    = blockIdx.x;
    const int tid  = threadIdx.x;
    const int w    = tid >> 6;         // wave 0..3
    const int l    = tid & 63;         // lane
    const bool fw  = (w < 2);          // team: forward / backward
    const int  wt  = w & 1;            // wave within team 0..1
    const int  hw  = 64 * wt;          // team-local half / k-slice base
    const int  team = fw ? 0 : 1;

    __shared__ float xchg[2][2][2][64];  // [team][parity][dst wave][lane]
    __shared__ float maskv[S_LEN];       // per-step mask as float
    __shared__ float aF[2][NT];          // alpha_255 / beta_255 gather
    __shared__ float nred[2];
    __shared__ int   cred[2];

    const float* em_b = em + (size_t)b * S_LEN * NT;
    const int*   tg_b = tags + (size_t)b * S_LEN;
    const float* emj  = em_b + hw + l;   // per-lane emission column (own half)

    // ---- stage per-step masks ----
    for (int q = tid; q < S_LEN; q += 256)
        maskv[q] = (tg_b[q] != PAD) ? 1.0f : 0.0f;

    // ---- numerator partial + valid count (forward team only) ----
    if (fw) {
        float numSum = 0.f;
        int   cnt    = 0;
        #pragma unroll
        for (int q = 0; q < 4; ++q) {
            int t  = 64 * (4 * wt + q) + l;
            int tv = tg_b[t];
            cnt += (tv != PAD) ? 1 : 0;
            float emg = em_b[(size_t)t * NT + tv];
            if (t == 0) {
                numSum += startT[tv] + emg;
            } else {
                int tp = tg_b[t - 1];
                float v = trans[tp * NT + tv] + emg;
                numSum += (tv != PAD) ? v : 0.f;
            }
        }
        #pragma unroll
        for (int off = 32; off > 0; off >>= 1) {
            numSum += __shfl_down(numSum, off, 64);
            cnt    += __shfl_down(cnt, off, 64);
        }
        if (l == 0) { nred[wt] = numSum; cred[wt] = cnt; }
    }

    // ---- k-pair column registers (direction-dependent orientation) ----
    // fwd: partial for j=l / j=64+l over k in [hw,hw+64):   expT[k][j]
    // bwd: partial for k=l / k=64+l over j in [hw,hw+64):   expT[k][j], j-slice
    float cXx[32], cXy[32], cYx[32], cYy[32];
    if (fw) {
        #pragma unroll
        for (int p = 0; p < 32; ++p) {
            int k = hw + 2 * p;
            cXx[p] = __expf(trans[k * NT + l]);
            cXy[p] = __expf(trans[(k + 1) * NT + l]);
            cYx[p] = __expf(trans[k * NT + 64 + l]);
            cYy[p] = __expf(trans[(k + 1) * NT + 64 + l]);
        }
    } else {
        #pragma unroll
        for (int p = 0; p < 32; ++p) {
            int j = hw + 2 * p;
            cXx[p] = __expf(trans[l * NT + j]);
            cXy[p] = __expf(trans[l * NT + j + 1]);
            cYx[p] = __expf(trans[(64 + l) * NT + j]);
            cYy[p] = __expf(trans[(64 + l) * NT + j + 1]);
        }
    }

    // ---- state init: fwd alpha_0, bwd beta_511 ----
    float aO = fw ? __expf(startT[hw + l] + em_b[hw + l])
                  : __expf(endT[hw + l]);

    // ---- em pipeline: slot s holds em[t(I=s+1)][hw+l]; t(I) = fw? I : 512-I ----
    float rE0 = emj[(size_t)(fw ? 1 : 511) * NT];
    float rE1 = emj[(size_t)(fw ? 2 : 510) * NT];
    float rE2 = emj[(size_t)(fw ? 3 : 509) * NT];
    float rE3 = emj[(size_t)(fw ? 4 : 508) * NT];
    float rE4 = emj[(size_t)(fw ? 5 : 507) * NT];
    float rE5 = emj[(size_t)(fw ? 6 : 506) * NT];
    float rE6 = emj[(size_t)(fw ? 7 : 505) * NT];
    float rE7 = emj[(size_t)(fw ? 8 : 504) * NT];

    __syncthreads();   // maskv + nred visible; one-time full barrier

#define STEP(SL, I, RN)                                                      \
  {                                                                          \
    const int i_   = (I);                                                    \
    const int t_   = fw ? (i_ <= 255 ? i_ : 255) : 512 - i_;                 \
    const int ti_  = i_ + 8;                                                 \
    const int tn_  = fw ? (ti_ <= 255 ? ti_ : 255)                           \
                        : (ti_ <= 256 ? 512 - ti_ : 256);                    \
    const int par_ = i_ & 1;                                                 \
    float nE_ = emj[(size_t)tn_ * NT];                                       \
    float mv_ = maskv[t_];                                                   \
    if (fw && i_ == 256) mv_ = 0.0f;      /* forward dummy step */           \
    float e_  = __expf(rE##SL);                                              \
    rE##SL = nE_;                                                            \
    float vin_ = fw ? aO : aO * e_;       /* bwd folds em BEFORE matvec */   \
    float aX0_ = 0.f, aX1_ = 0.f, aY0_ = 0.f, aY1_ = 0.f;                    \
    _Pragma("unroll")                                                        \
    for (int p_ = 0; p_ < 32; ++p_) {                                        \
      float s0_ = bcastf(vin_, 2 * p_);                                      \
      float s1_ = bcastf(vin_, 2 * p_ + 1);                                  \
      aX0_ += s0_ * cXx[p_];  aX1_ += s1_ * cXy[p_];                         \
      aY0_ += s0_ * cYx[p_];  aY1_ += s1_ * cYy[p_];                         \
    }                                                                        \
    float pX_ = aX0_ + aX1_;              /* partial for (j|k) = l      */   \
    float pY_ = aY0_ + aY1_;              /* partial for (j|k) = 64 + l */   \
    float keep_ = (wt == 0) ? pX_ : pY_;                                     \
    float ship_ = (wt == 0) ? pY_ : pX_;                                     \
    xchg[team][par_][1 ^ wt][l] = ship_;  /* one ds_write_b32 */             \
    lds_barrier();                                                           \
    float oth_  = xchg[team][par_][wt][l];                                   \
    float sum_  = keep_ + oth_;                                              \
    float comb_ = fw ? sum_ * e_ : sum_;  /* fwd folds em AFTER matvec */    \
    aO = (mv_ != 0.0f) ? comb_ : aO;                                         \
    if (RN) aO *= RENORM;                                                    \
  }

    // chunk 0: I = 1..8
    STEP(0, 1, false) STEP(1, 2, false) STEP(2, 3, false) STEP(3, 4, false)
    STEP(4, 5, false) STEP(5, 6, false) STEP(6, 7, false) STEP(7, 8, false)

    // chunks 1..31: I = 8c+1 .. 8c+8 ; renorm at I = 8c+1 (31 per team)
    for (int c = 1; c < 32; ++c) {
        const int i0 = 8 * c;
        STEP(0, i0 + 1, true)
        STEP(1, i0 + 2, false) STEP(2, i0 + 3, false) STEP(3, i0 + 4, false)
        STEP(4, i0 + 5, false) STEP(5, i0 + 6, false) STEP(6, i0 + 7, false)
        STEP(7, i0 + 8, false)
    }
#undef STEP

    // ---- in-block combine: den = log(dot(alpha_255, beta_255)) + 62^2 ln2 ----
    aF[team][hw + l] = aO;
    __syncthreads();

    if (w == 0) {
        float pe = aF[0][l] * aF[1][l] + aF[0][64 + l] * aF[1][64 + l];
        #pragma unroll
        for (int off = 32; off > 0; off >>= 1)
            pe += __shfl_down(pe, off, 64);
        if (l == 0) {
            int   cT   = cred[0] + cred[1];
            int   last = tg_b[cT - 1];
            float num  = nred[0] + nred[1] + endT[last];
            float den  = 62.0f * 62.0f * LN2F + logf(pe);
            atomicAdd(out, (num - den) * (1.0f / (float)B_SZ));
        }
    }
}

extern "C" void kernel_launch(void* const* d_in, const int* in_sizes, int n_in,
                              void* d_out, int out_size, void* d_ws, size_t ws_size,
                              hipStream_t stream) {
    const float* em     = (const float*)d_in[0];
    const int*   tags   = (const int*)d_in[1];
    const float* startT = (const float*)d_in[2];
    const float* endT   = (const float*)d_in[3];
    const float* trans  = (const float*)d_in[4];
    float* out = (float*)d_out;

    hipMemsetAsync(out, 0, sizeof(float), stream);
    crf_fb<<<B_SZ, 256, 0, stream>>>(em, tags, startT, endT, trans, out);
}